// Round 2
// baseline (100.741 us; speedup 1.0000x reference)
//
#include <hip/hip_runtime.h>

// Fast Walsh-Hadamard Transform along last dim (4096), scale 1/64.
// x: (rows, 4096) f32  ->  y: (rows, 4096) f32, y = FWHT(x)/64 == x @ H.
//
// Layout: padded LDS, float addr A(d) = d + 4*(d>>6)  (one float4 pad per
// 64-float row). All phase accesses are <=2-way bank aliased (free), and
// phase-2 offsets are compile-time -> ds_read2_b32/ds_write2_b32 fusion.

constexpr int DIMV = 4096;
constexpr int LDS_FLOATS = DIMV + (DIMV / 64) * 4;  // 4352 floats = 17 KB

__device__ __forceinline__ void bf(float& a, float& b) {
    float t = a + b;
    b = a - b;
    a = t;
}

__device__ __forceinline__ void bf4(float4& a, float4& b) {
    bf(a.x, b.x); bf(a.y, b.y); bf(a.z, b.z); bf(a.w, b.w);
}

__device__ __forceinline__ void fwht16(float (&w)[16]) {
#pragma unroll
    for (int s = 1; s < 16; s <<= 1) {
#pragma unroll
        for (int i = 0; i < 16; ++i) {
            if ((i & s) == 0) bf(w[i], w[i | s]);
        }
    }
}

__global__ __launch_bounds__(256) void fwht4096_kernel(const float* __restrict__ x,
                                                       float* __restrict__ y) {
    __shared__ __align__(16) float lds[LDS_FLOATS];
    const int tid = threadIdx.x;
    const long long row = blockIdx.x;

    const float4* xr = reinterpret_cast<const float4*>(x) + row * (DIMV / 4);
    float*        yrow = y + row * DIMV;
    float4*       l4 = reinterpret_cast<float4*>(lds);

    // ---- Load: thread holds elements d = 4*tid + k + 1024*q (k in float4, q=0..3)
    float4 v[4];
#pragma unroll
    for (int q = 0; q < 4; ++q) v[q] = xr[tid + 256 * q];

    const float sc = 0.015625f;  // 1/64 = 1/sqrt(4096)
#pragma unroll
    for (int q = 0; q < 4; ++q) { v[q].x *= sc; v[q].y *= sc; v[q].z *= sc; v[q].w *= sc; }

    // ---- Phase 1: element bits {0,1} (within float4) and {10,11} (across q)
#pragma unroll
    for (int q = 0; q < 4; ++q) {
        bf(v[q].x, v[q].y); bf(v[q].z, v[q].w);   // bit 0 (stride 1)
        bf(v[q].x, v[q].z); bf(v[q].y, v[q].w);   // bit 1 (stride 2)
    }
    bf4(v[0], v[1]); bf4(v[2], v[3]);             // bit 10 (stride 1024)
    bf4(v[0], v[2]); bf4(v[1], v[3]);             // bit 11 (stride 2048)

    // ---- To LDS (padded), b128 writes: float4 slot s -> s + (s>>4)
#pragma unroll
    for (int q = 0; q < 4; ++q) {
        const int s = tid + 256 * q;
        l4[s + (s >> 4)] = v[q];
    }
    __syncthreads();

    // ---- Phase 2: element bits {2..5}. d = k + 4*t + 64*h, A = k + 4t + 68h
    // Compile-time offsets 4*t -> ds_read2/write2 fusion; banks (k+4h+4t)%32 = 2-way.
    {
        const int k = tid & 3;
        const int h = tid >> 2;          // element bits 6..11
        const int base = k + 68 * h;
        float w[16];
#pragma unroll
        for (int t = 0; t < 16; ++t) w[t] = lds[base + 4 * t];
        fwht16(w);
#pragma unroll
        for (int t = 0; t < 16; ++t) lds[base + 4 * t] = w[t];
    }
    __syncthreads();

    // ---- Phase 3: element bits {6..9}. d = k + 4c + 64m + 1024u, A = k + 4c + 68m + 1088u
    // Then store DIRECTLY to global: for fixed m, a wave covers 256 contiguous bytes.
    {
        const int k = tid & 3;
        const int c = (tid >> 2) & 15;   // element bits 2..5
        const int u = tid >> 6;          // element bits 10,11 (wave id)
        const int base = k + 4 * c + 1088 * u;
        float w[16];
#pragma unroll
        for (int m = 0; m < 16; ++m) w[m] = lds[base + 68 * m];
        fwht16(w);
        const int gbase = k + 4 * c + 1024 * u;
#pragma unroll
        for (int m = 0; m < 16; ++m) yrow[gbase + 64 * m] = w[m];
    }
}

extern "C" void kernel_launch(void* const* d_in, const int* in_sizes, int n_in,
                              void* d_out, int out_size, void* d_ws, size_t ws_size,
                              hipStream_t stream) {
    const float* x = (const float*)d_in[0];
    float* y = (float*)d_out;
    const int rows = in_sizes[0] / DIMV;  // 4 * 4096 = 16384
    dim3 grid(rows), block(256);
    hipLaunchKernelGGL(fwht4096_kernel, grid, block, 0, stream, x, y);
}

// Round 6
// 91.409 us; speedup vs baseline: 1.1021x; 1.1021x over previous
//
#include <hip/hip_runtime.h>

// Wave-private FWHT-4096, y = x @ H = FWHT(x)/64.
// ONE ROW PER 64-THREAD BLOCK (1 wave). __syncthreads() in a single-wave
// workgroup compiles to a pure memory fence (no cross-wave coupling).
//
// Radix 6+6: P1 in registers (bits {0,1} inside float4 + {8..11} across the
// 16 float4s), one LDS transpose, P2 fwht64 in registers (bits {2..7}),
// write back, read in load layout, coalesced non-temporal float4 stores.
//
// LDS: 1024 float4 slots (16 KB), XOR swizzle slot' = s ^ ((s>>6)&7):
//  - stage writes / final reads (b128): 64 consecutive (permuted) slots -> minimal.
//  - P2 scalar r/w: bank = (4*((m^(h&7))&7) + k) % 32 -> exactly 2 lanes/bank (free).

constexpr int DIMV = 4096;

typedef float f32x4 __attribute__((ext_vector_type(4)));  // native vec for NT builtins

__device__ __forceinline__ void bf(float& a, float& b) {
    float t = a + b;
    b = a - b;
    a = t;
}
__device__ __forceinline__ void bf4(f32x4& a, f32x4& b) {
    f32x4 t = a + b;
    b = a - b;
    a = t;
}
// In-float4 FWHT on bits {0,1} (elements 0..3) — explicit temps, since
// ext_vector elements can't bind to float&.
__device__ __forceinline__ void fwht4_inner(f32x4& v) {
    float a = v.x, b = v.y, c = v.z, d = v.w;
    float t0 = a + b, t1 = a - b, t2 = c + d, t3 = c - d;
    v.x = t0 + t2;
    v.y = t1 + t3;
    v.z = t0 - t2;
    v.w = t1 - t3;
}

__global__ __launch_bounds__(64) void fwht4096_kernel(const float* __restrict__ x,
                                                      float* __restrict__ y) {
    __shared__ __align__(16) f32x4 l4[1024];
    float* lf = reinterpret_cast<float*>(l4);
    const int lane = threadIdx.x;
    const long long row = blockIdx.x;

    const f32x4* xr = reinterpret_cast<const f32x4*>(x) + row * (DIMV / 4);
    f32x4*       yr = reinterpret_cast<f32x4*>(y)       + row * (DIMV / 4);

    // ---- Load 16 float4 (non-temporal, streaming): element d = 4*lane + k + 256*q
    f32x4 v[16];
#pragma unroll
    for (int q = 0; q < 16; ++q) v[q] = __builtin_nontemporal_load(&xr[lane + 64 * q]);

    const float sc = 0.015625f;  // 1/64 = 1/sqrt(4096)
#pragma unroll
    for (int q = 0; q < 16; ++q) v[q] *= sc;

    // ---- P1a: bits 0,1 (inside each float4)
#pragma unroll
    for (int q = 0; q < 16; ++q) fwht4_inner(v[q]);

    // ---- P1b: bits 8..11 (across q)
#pragma unroll
    for (int s = 1; s < 16; s <<= 1) {
#pragma unroll
        for (int q = 0; q < 16; ++q) {
            if (!(q & s)) bf4(v[q], v[q | s]);
        }
    }

    // ---- Stage to LDS: slot s = lane + 64q, swizzled (lane ^ (q&7)) + 64q
#pragma unroll
    for (int q = 0; q < 16; ++q) l4[(lane ^ (q & 7)) + 64 * q] = v[q];

    __syncthreads();  // single-wave: pure lgkmcnt fence

    // ---- P2: lane owns (k = lane&3, h = lane>>2); d = k + 4m + 256h, m = 0..63
    {
        const int k = lane & 3;
        const int h = lane >> 2;
        const int hx = h & 7;
        const int base = 256 * h + k;   // float units
        float p[64];
#pragma unroll
        for (int m = 0; m < 64; ++m) p[m] = lf[base + 4 * (m ^ hx)];
        // fwht64 over bits 2..7
#pragma unroll
        for (int s = 1; s < 64; s <<= 1) {
#pragma unroll
            for (int i = 0; i < 64; ++i) {
                if (!(i & s)) bf(p[i], p[i | s]);
            }
        }
#pragma unroll
        for (int m = 0; m < 64; ++m) lf[base + 4 * (m ^ hx)] = p[m];
    }

    __syncthreads();  // single-wave: pure lgkmcnt fence

    // ---- Read back in load layout, coalesced non-temporal float4 stores
#pragma unroll
    for (int q = 0; q < 16; ++q) {
        f32x4 o = l4[(lane ^ (q & 7)) + 64 * q];
        __builtin_nontemporal_store(o, &yr[lane + 64 * q]);
    }
}

extern "C" void kernel_launch(void* const* d_in, const int* in_sizes, int n_in,
                              void* d_out, int out_size, void* d_ws, size_t ws_size,
                              hipStream_t stream) {
    const float* x = (const float*)d_in[0];
    float* y = (float*)d_out;
    const int rows = in_sizes[0] / DIMV;  // 16384
    dim3 grid(rows), block(64);
    hipLaunchKernelGGL(fwht4096_kernel, grid, block, 0, stream, x, y);
}